// Round 6
// baseline (156.226 us; speedup 1.0000x reference)
//
#include <hip/hip_runtime.h>
#include <hip/hip_bf16.h>

#define TPB 256
#define BATCH 262144
// One row of the batch is handled by a LANE PAIR (tid, tid^1):
//   layer1 split over K (each lane does 32 of 64 inputs),
//   middle (layer2 + circuit) computed redundantly (~460 FMA, cheap),
//   H1 split over outputs, H2 split over K, stores split 8+8.
// 2048 blocks * 4 waves = 8192 waves -> 32 waves/CU (vs 16 before).

__device__ __forceinline__ float fast_tanh(float x) {
    float ax = fabsf(x);
    float e  = __expf(-2.0f * ax);
    float t  = (1.0f - e) * __builtin_amdgcn_rcpf(1.0f + e);
    return copysignf(t, x);
}

template <int MASK>
__device__ __forceinline__ void ry_gate(float* psi, float c, float s) {
#pragma unroll
    for (int i = 0; i < 16; i++) {
        if (!(i & MASK)) {
            float a = psi[i], b = psi[i | MASK];
            psi[i]        = c * a - s * b;
            psi[i | MASK] = s * a + c * b;
        }
    }
}

template <int CM, int TM>
__device__ __forceinline__ void cnot_gate(float* psi) {
#pragma unroll
    for (int i = 0; i < 16; i++) {
        if ((i & CM) && !(i & TM)) {
            float t = psi[i];
            psi[i] = psi[i | TM];
            psi[i | TM] = t;
        }
    }
}

__global__ __launch_bounds__(TPB) void qnet_kernel(
    const float* __restrict__ state,
    const float* __restrict__ W1, const float* __restrict__ b1,
    const float* __restrict__ W2, const float* __restrict__ b2,
    const float* __restrict__ qp,
    const float* __restrict__ H1, const float* __restrict__ c1,
    const float* __restrict__ H2, const float* __restrict__ c2,
    float* __restrict__ out)
{
    __shared__ float sW1[2048];
    __shared__ float sb1[32];
    __shared__ float sW2[128];
    __shared__ float sb2[4];
    __shared__ float sH1[128];
    __shared__ float sc1[32];
    __shared__ float sH2[512];
    __shared__ float sc2[16];
    __shared__ float sQc[8], sQs[8];

    const int tid = threadIdx.x;
    for (int i = tid; i < 2048; i += TPB) sW1[i] = W1[i];
    for (int i = tid; i < 512;  i += TPB) sH2[i] = H2[i];
    if (tid < 128) { sW2[tid] = W2[tid]; sH1[tid] = H1[tid]; }
    if (tid < 32)  { sb1[tid] = b1[tid]; sc1[tid] = c1[tid]; }
    if (tid < 16)  { sc2[tid] = c2[tid]; }
    if (tid < 4)   { sb2[tid] = b2[tid]; }
    if (tid < 8) {
        float s, c;
        __sincosf(0.5f * qp[tid], &s, &c);
        sQs[tid] = s; sQc[tid] = c;
    }
    __syncthreads();

    const int half = tid & 1;
    const int row  = blockIdx.x * (TPB / 2) + (tid >> 1);

    // ------------- Layer 1 (K-split): hp[j] = sum over my 32 inputs -------------
    const float4* x4 = reinterpret_cast<const float4*>(
        state + (size_t)row * 64 + half * 32);

    float hp[32];
#pragma unroll
    for (int j = 0; j < 32; j++) hp[j] = 0.0f;

#pragma unroll
    for (int ic = 0; ic < 2; ic++) {            // 2 chunks of 16 inputs
        float4 xr[4];
#pragma unroll
        for (int k = 0; k < 4; k++) xr[k] = x4[ic * 4 + k];

#pragma unroll
        for (int j = 0; j < 32; j++) {
            const float4* w4 = reinterpret_cast<const float4*>(
                sW1 + j * 64 + half * 32 + ic * 16);
#pragma unroll
            for (int k = 0; k < 4; k++) {
                float4 w = w4[k];
                hp[j] = fmaf(xr[k].x, w.x, hp[j]);
                hp[j] = fmaf(xr[k].y, w.y, hp[j]);
                hp[j] = fmaf(xr[k].z, w.z, hp[j]);
                hp[j] = fmaf(xr[k].w, w.w, hp[j]);
            }
        }
    }

    // combine halves + bias + relu -> full h[32] in both lanes of the pair
    float h[32];
#pragma unroll
    for (int j = 0; j < 32; j++)
        h[j] = fmaxf(hp[j] + __shfl_xor(hp[j], 1) + sb1[j], 0.0f);

    // ------------- encoded = tanh(h @ W2^T + b2)  (redundant in pair) -------------
    float e[4];
#pragma unroll
    for (int w = 0; w < 4; w++) {
        float acc = sb2[w];
        const float4* w4 = reinterpret_cast<const float4*>(sW2 + w * 32);
#pragma unroll
        for (int k = 0; k < 8; k++) {
            float4 wv = w4[k];
            acc = fmaf(h[k * 4 + 0], wv.x, acc);
            acc = fmaf(h[k * 4 + 1], wv.y, acc);
            acc = fmaf(h[k * 4 + 2], wv.z, acc);
            acc = fmaf(h[k * 4 + 3], wv.w, acc);
        }
        e[w] = fast_tanh(acc);
    }

    // ------------- 4-qubit circuit (redundant in pair) -------------
    float qf[4];
    {
        float psi[16];
#pragma unroll
        for (int i = 0; i < 16; i++) psi[i] = 0.0f;
        psi[0] = 1.0f;

        float s, c;
        __sincosf(0.5f * e[0], &s, &c); ry_gate<8>(psi, c, s);
        __sincosf(0.5f * e[1], &s, &c); ry_gate<4>(psi, c, s);
        __sincosf(0.5f * e[2], &s, &c); ry_gate<2>(psi, c, s);
        __sincosf(0.5f * e[3], &s, &c); ry_gate<1>(psi, c, s);

#pragma unroll
        for (int layer = 0; layer < 2; layer++) {
            cnot_gate<8, 4>(psi);
            cnot_gate<4, 2>(psi);
            cnot_gate<2, 1>(psi);
            cnot_gate<1, 8>(psi);
            ry_gate<8>(psi, sQc[layer * 4 + 0], sQs[layer * 4 + 0]);
            ry_gate<4>(psi, sQc[layer * 4 + 1], sQs[layer * 4 + 1]);
            ry_gate<2>(psi, sQc[layer * 4 + 2], sQs[layer * 4 + 2]);
            ry_gate<1>(psi, sQc[layer * 4 + 3], sQs[layer * 4 + 3]);
        }

        float p[16];
#pragma unroll
        for (int i = 0; i < 16; i++) p[i] = psi[i] * psi[i];
#pragma unroll
        for (int w = 0; w < 4; w++) {
            const int m = 8 >> w;
            float z = 0.0f;
#pragma unroll
            for (int i = 0; i < 16; i++) z += (i & m) ? -p[i] : p[i];
            qf[w] = z;
        }
    }

    // ------------- h2 = relu(qf @ H1^T + c1), output-split: my 16 of 32 -------------
    const int jb = half * 16;
    float h2[16];
#pragma unroll
    for (int jj = 0; jj < 16; jj++) {
        const int j = jb + jj;
        const float4 hv = *reinterpret_cast<const float4*>(sH1 + j * 4);
        float a = sc1[j];
        a = fmaf(qf[0], hv.x, a);
        a = fmaf(qf[1], hv.y, a);
        a = fmaf(qf[2], hv.z, a);
        a = fmaf(qf[3], hv.w, a);
        h2[jj] = fmaxf(a, 0.0f);
    }

    // ------------- H2 layer, K-split partials over my h2[16] -------------
    float po[16];
#pragma unroll
    for (int o = 0; o < 16; o++) {
        const float4* w4 = reinterpret_cast<const float4*>(sH2 + o * 32 + jb);
        float acc = half ? 0.0f : sc2[o];
#pragma unroll
        for (int k = 0; k < 4; k++) {
            float4 wv = w4[k];
            acc = fmaf(h2[k * 4 + 0], wv.x, acc);
            acc = fmaf(h2[k * 4 + 1], wv.y, acc);
            acc = fmaf(h2[k * 4 + 2], wv.z, acc);
            acc = fmaf(h2[k * 4 + 3], wv.w, acc);
        }
        po[o] = acc;
    }

    // combine pair partials for all 16 outputs (both lanes pass same o)
    float tot[16];
#pragma unroll
    for (int o = 0; o < 16; o++) tot[o] = po[o] + __shfl_xor(po[o], 1);

    // tanh + store only my 8 outputs
    const int ob = half * 8;
    float qv[8];
#pragma unroll
    for (int oo = 0; oo < 8; oo++) qv[oo] = fast_tanh(tot[ob + oo]);

    float4* dst = reinterpret_cast<float4*>(out + (size_t)row * 16 + ob);
    dst[0] = make_float4(qv[0], qv[1], qv[2], qv[3]);
    dst[1] = make_float4(qv[4], qv[5], qv[6], qv[7]);
}

extern "C" void kernel_launch(void* const* d_in, const int* in_sizes, int n_in,
                              void* d_out, int out_size, void* d_ws, size_t ws_size,
                              hipStream_t stream) {
    const float* state = (const float*)d_in[0];
    const float* W1    = (const float*)d_in[1];
    const float* b1    = (const float*)d_in[2];
    const float* W2    = (const float*)d_in[3];
    const float* b2    = (const float*)d_in[4];
    const float* qp    = (const float*)d_in[5];
    const float* H1    = (const float*)d_in[6];
    const float* c1    = (const float*)d_in[7];
    const float* H2    = (const float*)d_in[8];
    const float* c2    = (const float*)d_in[9];
    float* out = (float*)d_out;

    const int blocks = BATCH / (TPB / 2);   // 2048
    qnet_kernel<<<blocks, TPB, 0, stream>>>(state, W1, b1, W2, b2, qp,
                                            H1, c1, H2, c2, out);
}

// Round 7
// 138.122 us; speedup vs baseline: 1.1311x; 1.1311x over previous
//
#include <hip/hip_runtime.h>
#include <hip/hip_bf16.h>

#define TPB 256
#define BATCH 262144
// One row per thread, NO LDS: all weights/biases are read with wave-uniform
// (compile-time) indices directly from the kernel-arg pointers -> the
// compiler scalarizes them into s_load (SGPR operands feed v_fma directly).
// This moves ~700 ds_read_b128/thread of broadcast traffic off the LDS pipe
// (which was saturated: 16 waves/CU * 704 * 12cyc ~= the whole kernel time).
// Grid caps at 4096 waves (4/SIMD) so VGPR<=128 is free: __launch_bounds__(256,4).

__device__ __forceinline__ float fast_tanh(float x) {
    float ax = fabsf(x);
    float e  = __expf(-2.0f * ax);
    float t  = (1.0f - e) * __builtin_amdgcn_rcpf(1.0f + e);
    return copysignf(t, x);
}

template <int MASK>
__device__ __forceinline__ void ry_gate(float* psi, float c, float s) {
#pragma unroll
    for (int i = 0; i < 16; i++) {
        if (!(i & MASK)) {
            float a = psi[i], b = psi[i | MASK];
            psi[i]        = c * a - s * b;
            psi[i | MASK] = s * a + c * b;
        }
    }
}

template <int CM, int TM>
__device__ __forceinline__ void cnot_gate(float* psi) {
#pragma unroll
    for (int i = 0; i < 16; i++) {
        if ((i & CM) && !(i & TM)) {
            float t = psi[i];
            psi[i] = psi[i | TM];
            psi[i | TM] = t;
        }
    }
}

__global__ __launch_bounds__(TPB, 4) void qnet_kernel(
    const float* __restrict__ state,
    const float* __restrict__ W1, const float* __restrict__ b1,
    const float* __restrict__ W2, const float* __restrict__ b2,
    const float* __restrict__ qp,
    const float* __restrict__ H1, const float* __restrict__ c1,
    const float* __restrict__ H2, const float* __restrict__ c2,
    float* __restrict__ out)
{
    const int bidx = blockIdx.x * TPB + threadIdx.x;

    // ---- load full input row (64 floats) ----
    const float4* x4 = reinterpret_cast<const float4*>(state + (size_t)bidx * 64);
    float x[64];
#pragma unroll
    for (int k = 0; k < 16; k++) {
        float4 v = x4[k];
        x[k * 4 + 0] = v.x; x[k * 4 + 1] = v.y;
        x[k * 4 + 2] = v.z; x[k * 4 + 3] = v.w;
    }

    // ---------------- Layer 1: h = relu(x @ W1^T + b1) ----------------
    float h[32];
#pragma unroll
    for (int j = 0; j < 32; j++) {
        float acc = b1[j];                  // uniform -> s_load
#pragma unroll
        for (int k = 0; k < 64; k++)
            acc = fmaf(x[k], W1[j * 64 + k], acc);   // W1: uniform s_load operand
        h[j] = fmaxf(acc, 0.0f);
    }

    // ---------------- encoded = tanh(h @ W2^T + b2) ----------------
    float e[4];
#pragma unroll
    for (int w = 0; w < 4; w++) {
        float acc = b2[w];
#pragma unroll
        for (int k = 0; k < 32; k++)
            acc = fmaf(h[k], W2[w * 32 + k], acc);
        e[w] = fast_tanh(acc);
    }

    // ---------------- 4-qubit circuit ----------------
    float qf[4];
    {
        float psi[16];
#pragma unroll
        for (int i = 0; i < 16; i++) psi[i] = 0.0f;
        psi[0] = 1.0f;

        float s, c;
        __sincosf(0.5f * e[0], &s, &c); ry_gate<8>(psi, c, s);
        __sincosf(0.5f * e[1], &s, &c); ry_gate<4>(psi, c, s);
        __sincosf(0.5f * e[2], &s, &c); ry_gate<2>(psi, c, s);
        __sincosf(0.5f * e[3], &s, &c); ry_gate<1>(psi, c, s);

#pragma unroll
        for (int layer = 0; layer < 2; layer++) {
            cnot_gate<8, 4>(psi);
            cnot_gate<4, 2>(psi);
            cnot_gate<2, 1>(psi);
            cnot_gate<1, 8>(psi);
#pragma unroll
            for (int i = 0; i < 4; i++) {
                float s2, c2;
                __sincosf(0.5f * qp[layer * 4 + i], &s2, &c2);  // uniform
                if (i == 0) ry_gate<8>(psi, c2, s2);
                if (i == 1) ry_gate<4>(psi, c2, s2);
                if (i == 2) ry_gate<2>(psi, c2, s2);
                if (i == 3) ry_gate<1>(psi, c2, s2);
            }
        }

        float p[16];
#pragma unroll
        for (int i = 0; i < 16; i++) p[i] = psi[i] * psi[i];
#pragma unroll
        for (int w = 0; w < 4; w++) {
            const int m = 8 >> w;
            float z = 0.0f;
#pragma unroll
            for (int i = 0; i < 16; i++) z += (i & m) ? -p[i] : p[i];
            qf[w] = z;
        }
    }

    // ---------------- h2 = relu(qf @ H1^T + c1) ----------------
    float h2[32];
#pragma unroll
    for (int j = 0; j < 32; j++) {
        float a = c1[j];
        a = fmaf(qf[0], H1[j * 4 + 0], a);
        a = fmaf(qf[1], H1[j * 4 + 1], a);
        a = fmaf(qf[2], H1[j * 4 + 2], a);
        a = fmaf(qf[3], H1[j * 4 + 3], a);
        h2[j] = fmaxf(a, 0.0f);
    }

    // ---------------- q = tanh(h2 @ H2^T + c2), store f32 ----------------
    float qv[16];
#pragma unroll
    for (int o = 0; o < 16; o++) {
        float acc = c2[o];
#pragma unroll
        for (int k = 0; k < 32; k++)
            acc = fmaf(h2[k], H2[o * 32 + k], acc);
        qv[o] = fast_tanh(acc);
    }

    float4* dst = reinterpret_cast<float4*>(out + (size_t)bidx * 16);
#pragma unroll
    for (int k = 0; k < 4; k++) {
        dst[k] = make_float4(qv[k * 4 + 0], qv[k * 4 + 1],
                             qv[k * 4 + 2], qv[k * 4 + 3]);
    }
}

extern "C" void kernel_launch(void* const* d_in, const int* in_sizes, int n_in,
                              void* d_out, int out_size, void* d_ws, size_t ws_size,
                              hipStream_t stream) {
    const float* state = (const float*)d_in[0];
    const float* W1    = (const float*)d_in[1];
    const float* b1    = (const float*)d_in[2];
    const float* W2    = (const float*)d_in[3];
    const float* b2    = (const float*)d_in[4];
    const float* qp    = (const float*)d_in[5];
    const float* H1    = (const float*)d_in[6];
    const float* c1    = (const float*)d_in[7];
    const float* H2    = (const float*)d_in[8];
    const float* c2    = (const float*)d_in[9];
    float* out = (float*)d_out;

    const int blocks = BATCH / TPB;   // 1024
    qnet_kernel<<<blocks, TPB, 0, stream>>>(state, W1, b1, W2, b2, qp,
                                            H1, c1, H2, c2, out);
}

// Round 8
// 119.783 us; speedup vs baseline: 1.3042x; 1.1531x over previous
//
#include <hip/hip_runtime.h>
#include <hip/hip_bf16.h>

#define TPB 256
#define BATCH 262144
#define S 34   // LDS row stride in dwords (even -> 8B-aligned rows, <=2-way bank aliasing)

typedef _Float16 half8_t __attribute__((ext_vector_type(8)));
typedef float    f32x4   __attribute__((ext_vector_type(4)));

__device__ __forceinline__ float fast_tanh(float x) {
    float ax = fabsf(x);
    float e  = __expf(-2.0f * ax);
    float t  = (1.0f - e) * __builtin_amdgcn_rcpf(1.0f + e);
    return copysignf(t, x);
}

template <int MASK>
__device__ __forceinline__ void ry_gate(float* psi, float c, float s) {
#pragma unroll
    for (int i = 0; i < 16; i++) {
        if (!(i & MASK)) {
            float a = psi[i], b = psi[i | MASK];
            psi[i]        = c * a - s * b;
            psi[i | MASK] = s * a + c * b;
        }
    }
}

template <int CM, int TM>
__device__ __forceinline__ void cnot_gate(float* psi) {
#pragma unroll
    for (int i = 0; i < 16; i++) {
        if ((i & CM) && !(i & TM)) {
            float t = psi[i];
            psi[i] = psi[i | TM];
            psi[i | TM] = t;
        }
    }
}

__device__ __forceinline__ half8_t cvt8(float4 a, float4 b) {
    half8_t r;
    r[0] = (_Float16)a.x; r[1] = (_Float16)a.y; r[2] = (_Float16)a.z; r[3] = (_Float16)a.w;
    r[4] = (_Float16)b.x; r[5] = (_Float16)b.y; r[6] = (_Float16)b.z; r[7] = (_Float16)b.w;
    return r;
}

__global__ __launch_bounds__(TPB, 4) void qnet_kernel(
    const float* __restrict__ state,
    const float* __restrict__ W1, const float* __restrict__ b1,
    const float* __restrict__ W2, const float* __restrict__ b2,
    const float* __restrict__ qp,
    const float* __restrict__ H1, const float* __restrict__ c1,
    const float* __restrict__ H2, const float* __restrict__ c2,
    float* __restrict__ out)
{
    __shared__ float sh[4 * 64 * S];   // 34816 B, one 64xS slice per wave

    const int tid  = threadIdx.x;
    const int lane = tid & 63;
    const int wv   = tid >> 6;
    const int l15  = lane & 15;
    const int lq   = lane >> 4;                       // quad index 0..3
    const int rowBase = blockIdx.x * TPB + wv * 64;   // 64 rows per wave
    float* hb = sh + wv * 64 * S;

    // ---- B-fragments of W1 (B[k][n] = W1[n*64+k]); lane holds k=lq*8..+8, n=16u+l15 ----
    half8_t bW1[2][2];
#pragma unroll
    for (int u = 0; u < 2; u++)
#pragma unroll
        for (int kt = 0; kt < 2; kt++) {
            const float* p = W1 + (16 * u + l15) * 64 + 32 * kt + lq * 8;
            bW1[u][kt] = cvt8(*(const float4*)p, *(const float4*)(p + 4));
        }
    const float bias0 = b1[l15];
    const float bias1 = b1[16 + l15];

    // ---- Layer 1 via MFMA: A = x rows (A[m=l15][k=lq*8+j]) ----
    f32x4 acc[4][2];
#pragma unroll
    for (int mt = 0; mt < 4; mt++)
#pragma unroll
        for (int u = 0; u < 2; u++)
#pragma unroll
            for (int r = 0; r < 4; r++) acc[mt][u][r] = 0.0f;

#pragma unroll
    for (int kt = 0; kt < 2; kt++) {
#pragma unroll
        for (int mt = 0; mt < 4; mt++) {
            const float* p = state + (size_t)(rowBase + 16 * mt + l15) * 64 + 32 * kt + lq * 8;
            half8_t a = cvt8(*(const float4*)p, *(const float4*)(p + 4));
            acc[mt][0] = __builtin_amdgcn_mfma_f32_16x16x32_f16(a, bW1[0][kt], acc[mt][0], 0, 0, 0);
            acc[mt][1] = __builtin_amdgcn_mfma_f32_16x16x32_f16(a, bW1[1][kt], acc[mt][1], 0, 0, 0);
        }
    }

    // ---- h = relu(acc + b1) -> LDS rows (C layout: row=16mt+4lq+r, col=16u+l15) ----
#pragma unroll
    for (int mt = 0; mt < 4; mt++)
#pragma unroll
        for (int r = 0; r < 4; r++) {
            int row = 16 * mt + 4 * lq + r;
            hb[row * S + l15]      = fmaxf(acc[mt][0][r] + bias0, 0.0f);
            hb[row * S + 16 + l15] = fmaxf(acc[mt][1][r] + bias1, 0.0f);
        }
    __syncthreads();

    // ---- per-thread middle: my row = lane ----
    float h[32];
    {
        const float2* hr = reinterpret_cast<const float2*>(hb + lane * S);
#pragma unroll
        for (int j = 0; j < 16; j++) { float2 v = hr[j]; h[2 * j] = v.x; h[2 * j + 1] = v.y; }
    }

    // encoded = tanh(h @ W2^T + b2)   (W2 via uniform s_load)
    float e[4];
#pragma unroll
    for (int w = 0; w < 4; w++) {
        float a = b2[w];
#pragma unroll
        for (int k = 0; k < 32; k++) a = fmaf(h[k], W2[w * 32 + k], a);
        e[w] = fast_tanh(a);
    }

    // 4-qubit circuit
    float qf[4];
    {
        float psi[16];
#pragma unroll
        for (int i = 0; i < 16; i++) psi[i] = 0.0f;
        psi[0] = 1.0f;

        float s, c;
        __sincosf(0.5f * e[0], &s, &c); ry_gate<8>(psi, c, s);
        __sincosf(0.5f * e[1], &s, &c); ry_gate<4>(psi, c, s);
        __sincosf(0.5f * e[2], &s, &c); ry_gate<2>(psi, c, s);
        __sincosf(0.5f * e[3], &s, &c); ry_gate<1>(psi, c, s);

#pragma unroll
        for (int layer = 0; layer < 2; layer++) {
            cnot_gate<8, 4>(psi);
            cnot_gate<4, 2>(psi);
            cnot_gate<2, 1>(psi);
            cnot_gate<1, 8>(psi);
#pragma unroll
            for (int i = 0; i < 4; i++) {
                float s2, c2v;
                __sincosf(0.5f * qp[layer * 4 + i], &s2, &c2v);
                if (i == 0) ry_gate<8>(psi, c2v, s2);
                if (i == 1) ry_gate<4>(psi, c2v, s2);
                if (i == 2) ry_gate<2>(psi, c2v, s2);
                if (i == 3) ry_gate<1>(psi, c2v, s2);
            }
        }

        float p[16];
#pragma unroll
        for (int i = 0; i < 16; i++) p[i] = psi[i] * psi[i];
#pragma unroll
        for (int w = 0; w < 4; w++) {
            const int m = 8 >> w;
            float z = 0.0f;
#pragma unroll
            for (int i = 0; i < 16; i++) z += (i & m) ? -p[i] : p[i];
            qf[w] = z;
        }
    }

    // h2 = relu(qf @ H1^T + c1)
    float h2[32];
#pragma unroll
    for (int j = 0; j < 32; j++) {
        float a = c1[j];
        a = fmaf(qf[0], H1[j * 4 + 0], a);
        a = fmaf(qf[1], H1[j * 4 + 1], a);
        a = fmaf(qf[2], H1[j * 4 + 2], a);
        a = fmaf(qf[3], H1[j * 4 + 3], a);
        h2[j] = fmaxf(a, 0.0f);
    }

    __syncthreads();   // all h reads done; reuse the buffer for h2

    {
        float2* hw = reinterpret_cast<float2*>(hb + lane * S);
#pragma unroll
        for (int j = 0; j < 16; j++) hw[j] = make_float2(h2[2 * j], h2[2 * j + 1]);
    }
    __syncthreads();

    // ---- H2 layer via MFMA: A = h2 rows (K=32), B[k][n] = H2[n*32+k], N=16 ----
    half8_t bH2;
    {
        const float* p = H2 + l15 * 32 + lq * 8;
        bH2 = cvt8(*(const float4*)p, *(const float4*)(p + 4));
    }

    f32x4 acc2[4];
#pragma unroll
    for (int mt = 0; mt < 4; mt++)
#pragma unroll
        for (int r = 0; r < 4; r++) acc2[mt][r] = 0.0f;

#pragma unroll
    for (int mt = 0; mt < 4; mt++) {
        const float2* q = reinterpret_cast<const float2*>(hb + (16 * mt + l15) * S + lq * 8);
        float2 a0 = q[0], a1 = q[1], a2 = q[2], a3 = q[3];
        half8_t a;
        a[0] = (_Float16)a0.x; a[1] = (_Float16)a0.y;
        a[2] = (_Float16)a1.x; a[3] = (_Float16)a1.y;
        a[4] = (_Float16)a2.x; a[5] = (_Float16)a2.y;
        a[6] = (_Float16)a3.x; a[7] = (_Float16)a3.y;
        acc2[mt] = __builtin_amdgcn_mfma_f32_16x16x32_f16(a, bH2, acc2[mt], 0, 0, 0);
    }

    // ---- epilogue: q = tanh(acc2 + c2), store (row, col=l15) ----
    const float cc = c2[l15];
#pragma unroll
    for (int mt = 0; mt < 4; mt++)
#pragma unroll
        for (int r = 0; r < 4; r++) {
            int row = rowBase + 16 * mt + 4 * lq + r;
            out[(size_t)row * 16 + l15] = fast_tanh(acc2[mt][r] + cc);
        }
}

extern "C" void kernel_launch(void* const* d_in, const int* in_sizes, int n_in,
                              void* d_out, int out_size, void* d_ws, size_t ws_size,
                              hipStream_t stream) {
    const float* state = (const float*)d_in[0];
    const float* W1    = (const float*)d_in[1];
    const float* b1    = (const float*)d_in[2];
    const float* W2    = (const float*)d_in[3];
    const float* b2    = (const float*)d_in[4];
    const float* qp    = (const float*)d_in[5];
    const float* H1    = (const float*)d_in[6];
    const float* c1    = (const float*)d_in[7];
    const float* H2    = (const float*)d_in[8];
    const float* c2    = (const float*)d_in[9];
    float* out = (float*)d_out;

    const int blocks = BATCH / TPB;   // 1024
    qnet_kernel<<<blocks, TPB, 0, stream>>>(state, W1, b1, W2, b2, qp,
                                            H1, c1, H2, c2, out);
}

// Round 10
// 118.722 us; speedup vs baseline: 1.3159x; 1.0089x over previous
//
#include <hip/hip_runtime.h>
#include <hip/hip_bf16.h>

#define TPB 256
#define BATCH 262144
#define S 34   // LDS row stride in dwords (even -> 8B rows, <=2-way bank aliasing)

typedef __fp16   fp16x2  __attribute__((ext_vector_type(2)));   // cvt_pkrtz result type
typedef _Float16 half8_t __attribute__((ext_vector_type(8)));
typedef float    f32x4   __attribute__((ext_vector_type(4)));

// Intra-wave LDS fence: waits for this wave's DS ops; LDS slices are
// per-wave so no block-wide __syncthreads is needed (saves 3 barriers).
#define WAVE_LDS_FENCE() asm volatile("s_waitcnt lgkmcnt(0)" ::: "memory")

__device__ __forceinline__ float fast_tanh(float x) {
    float ax = fabsf(x);
    float e  = __expf(-2.0f * ax);
    float t  = (1.0f - e) * __builtin_amdgcn_rcpf(1.0f + e);
    return copysignf(t, x);
}

template <int MASK>
__device__ __forceinline__ void ry_gate(float* psi, float c, float s) {
#pragma unroll
    for (int i = 0; i < 16; i++) {
        if (!(i & MASK)) {
            float a = psi[i], b = psi[i | MASK];
            psi[i]        = c * a - s * b;
            psi[i | MASK] = s * a + c * b;
        }
    }
}

template <int CM, int TM>
__device__ __forceinline__ void cnot_gate(float* psi) {
#pragma unroll
    for (int i = 0; i < 16; i++) {
        if ((i & CM) && !(i & TM)) {
            float t = psi[i];
            psi[i] = psi[i | TM];
            psi[i | TM] = t;
        }
    }
}

__device__ __forceinline__ half8_t cvt8(float4 a, float4 b) {
    fp16x2 p0 = __builtin_amdgcn_cvt_pkrtz(a.x, a.y);
    fp16x2 p1 = __builtin_amdgcn_cvt_pkrtz(a.z, a.w);
    fp16x2 p2 = __builtin_amdgcn_cvt_pkrtz(b.x, b.y);
    fp16x2 p3 = __builtin_amdgcn_cvt_pkrtz(b.z, b.w);
    half8_t r;
    r[0] = (_Float16)p0[0]; r[1] = (_Float16)p0[1];
    r[2] = (_Float16)p1[0]; r[3] = (_Float16)p1[1];
    r[4] = (_Float16)p2[0]; r[5] = (_Float16)p2[1];
    r[6] = (_Float16)p3[0]; r[7] = (_Float16)p3[1];
    return r;
}

__global__ __launch_bounds__(TPB, 4) void qnet_kernel(
    const float* __restrict__ state,
    const float* __restrict__ W1, const float* __restrict__ b1,
    const float* __restrict__ W2, const float* __restrict__ b2,
    const float* __restrict__ qp,
    const float* __restrict__ H1, const float* __restrict__ c1,
    const float* __restrict__ H2, const float* __restrict__ c2,
    float* __restrict__ out)
{
    __shared__ float sh[4 * 64 * S];   // one 64xS slice per wave

    const int tid  = threadIdx.x;
    const int lane = tid & 63;
    const int wv   = tid >> 6;
    const int l15  = lane & 15;
    const int lq   = lane >> 4;
    const int rowBase = blockIdx.x * TPB + wv * 64;
    float* hb = sh + wv * 64 * S;

    // ---- PREFETCH: issue all 8 state loads first (A fragments) ----
    float4 xa[4][2], xb[4][2];   // [mt][kt]
#pragma unroll
    for (int mt = 0; mt < 4; mt++) {
        const float* p0 = state + (size_t)(rowBase + 16 * mt + l15) * 64 + lq * 8;
#pragma unroll
        for (int kt = 0; kt < 2; kt++) {
            xa[mt][kt] = *(const float4*)(p0 + 32 * kt);
            xb[mt][kt] = *(const float4*)(p0 + 32 * kt + 4);
        }
    }

    // ---- B-fragments of W1 (B[k][n] = W1[n*64+k]) ----
    half8_t bW1[2][2];
#pragma unroll
    for (int u = 0; u < 2; u++)
#pragma unroll
        for (int kt = 0; kt < 2; kt++) {
            const float* p = W1 + (16 * u + l15) * 64 + 32 * kt + lq * 8;
            bW1[u][kt] = cvt8(*(const float4*)p, *(const float4*)(p + 4));
        }
    const float bias0 = b1[l15];
    const float bias1 = b1[16 + l15];

    // ---- Layer 1 via MFMA ----
    f32x4 acc[4][2];
#pragma unroll
    for (int mt = 0; mt < 4; mt++)
#pragma unroll
        for (int u = 0; u < 2; u++)
#pragma unroll
            for (int r = 0; r < 4; r++) acc[mt][u][r] = 0.0f;

#pragma unroll
    for (int kt = 0; kt < 2; kt++) {
#pragma unroll
        for (int mt = 0; mt < 4; mt++) {
            half8_t a = cvt8(xa[mt][kt], xb[mt][kt]);
            acc[mt][0] = __builtin_amdgcn_mfma_f32_16x16x32_f16(a, bW1[0][kt], acc[mt][0], 0, 0, 0);
            acc[mt][1] = __builtin_amdgcn_mfma_f32_16x16x32_f16(a, bW1[1][kt], acc[mt][1], 0, 0, 0);
        }
    }

    // ---- h = relu(acc + b1) -> LDS (C layout: row=16mt+4lq+r, col=16u+l15) ----
#pragma unroll
    for (int mt = 0; mt < 4; mt++)
#pragma unroll
        for (int r = 0; r < 4; r++) {
            int row = 16 * mt + 4 * lq + r;
            hb[row * S + l15]      = fmaxf(acc[mt][0][r] + bias0, 0.0f);
            hb[row * S + 16 + l15] = fmaxf(acc[mt][1][r] + bias1, 0.0f);
        }
    WAVE_LDS_FENCE();

    // ---- per-thread middle: my row = lane ----
    float h[32];
    {
        const float2* hr = reinterpret_cast<const float2*>(hb + lane * S);
#pragma unroll
        for (int j = 0; j < 16; j++) { float2 v = hr[j]; h[2 * j] = v.x; h[2 * j + 1] = v.y; }
    }

    float e[4];
#pragma unroll
    for (int w = 0; w < 4; w++) {
        float a = b2[w];
#pragma unroll
        for (int k = 0; k < 32; k++) a = fmaf(h[k], W2[w * 32 + k], a);
        e[w] = fast_tanh(a);
    }

    float qf[4];
    {
        float psi[16];
#pragma unroll
        for (int i = 0; i < 16; i++) psi[i] = 0.0f;
        psi[0] = 1.0f;

        float s, c;
        __sincosf(0.5f * e[0], &s, &c); ry_gate<8>(psi, c, s);
        __sincosf(0.5f * e[1], &s, &c); ry_gate<4>(psi, c, s);
        __sincosf(0.5f * e[2], &s, &c); ry_gate<2>(psi, c, s);
        __sincosf(0.5f * e[3], &s, &c); ry_gate<1>(psi, c, s);

#pragma unroll
        for (int layer = 0; layer < 2; layer++) {
            cnot_gate<8, 4>(psi);
            cnot_gate<4, 2>(psi);
            cnot_gate<2, 1>(psi);
            cnot_gate<1, 8>(psi);
#pragma unroll
            for (int i = 0; i < 4; i++) {
                float s2, c2v;
                __sincosf(0.5f * qp[layer * 4 + i], &s2, &c2v);
                if (i == 0) ry_gate<8>(psi, c2v, s2);
                if (i == 1) ry_gate<4>(psi, c2v, s2);
                if (i == 2) ry_gate<2>(psi, c2v, s2);
                if (i == 3) ry_gate<1>(psi, c2v, s2);
            }
        }

        float p[16];
#pragma unroll
        for (int i = 0; i < 16; i++) p[i] = psi[i] * psi[i];
#pragma unroll
        for (int w = 0; w < 4; w++) {
            const int m = 8 >> w;
            float z = 0.0f;
#pragma unroll
            for (int i = 0; i < 16; i++) z += (i & m) ? -p[i] : p[i];
            qf[w] = z;
        }
    }

    float h2[32];
#pragma unroll
    for (int j = 0; j < 32; j++) {
        float a = c1[j];
        a = fmaf(qf[0], H1[j * 4 + 0], a);
        a = fmaf(qf[1], H1[j * 4 + 1], a);
        a = fmaf(qf[2], H1[j * 4 + 2], a);
        a = fmaf(qf[3], H1[j * 4 + 3], a);
        h2[j] = fmaxf(a, 0.0f);
    }

    WAVE_LDS_FENCE();   // all h reads done; reuse buffer for h2
    {
        float2* hw = reinterpret_cast<float2*>(hb + lane * S);
#pragma unroll
        for (int j = 0; j < 16; j++) hw[j] = make_float2(h2[2 * j], h2[2 * j + 1]);
    }
    WAVE_LDS_FENCE();

    // ---- H2 layer via MFMA: B[k][n] = H2[n*32+k], N=16 ----
    half8_t bH2;
    {
        const float* p = H2 + l15 * 32 + lq * 8;
        bH2 = cvt8(*(const float4*)p, *(const float4*)(p + 4));
    }

    f32x4 acc2[4];
#pragma unroll
    for (int mt = 0; mt < 4; mt++)
#pragma unroll
        for (int r = 0; r < 4; r++) acc2[mt][r] = 0.0f;

#pragma unroll
    for (int mt = 0; mt < 4; mt++) {
        const float2* q = reinterpret_cast<const float2*>(hb + (16 * mt + l15) * S + lq * 8);
        float2 a0 = q[0], a1 = q[1], a2 = q[2], a3 = q[3];
        half8_t a = cvt8(make_float4(a0.x, a0.y, a1.x, a1.y),
                         make_float4(a2.x, a2.y, a3.x, a3.y));
        acc2[mt] = __builtin_amdgcn_mfma_f32_16x16x32_f16(a, bH2, acc2[mt], 0, 0, 0);
    }

    // ---- epilogue ----
    const float cc = c2[l15];
#pragma unroll
    for (int mt = 0; mt < 4; mt++)
#pragma unroll
        for (int r = 0; r < 4; r++) {
            int row = rowBase + 16 * mt + 4 * lq + r;
            out[(size_t)row * 16 + l15] = fast_tanh(acc2[mt][r] + cc);
        }
}

extern "C" void kernel_launch(void* const* d_in, const int* in_sizes, int n_in,
                              void* d_out, int out_size, void* d_ws, size_t ws_size,
                              hipStream_t stream) {
    const float* state = (const float*)d_in[0];
    const float* W1    = (const float*)d_in[1];
    const float* b1    = (const float*)d_in[2];
    const float* W2    = (const float*)d_in[3];
    const float* b2    = (const float*)d_in[4];
    const float* qp    = (const float*)d_in[5];
    const float* H1    = (const float*)d_in[6];
    const float* c1    = (const float*)d_in[7];
    const float* H2    = (const float*)d_in[8];
    const float* c2    = (const float*)d_in[9];
    float* out = (float*)d_out;

    const int blocks = BATCH / TPB;   // 1024
    qnet_kernel<<<blocks, TPB, 0, stream>>>(state, W1, b1, W2, b2, qp,
                                            H1, c1, H2, c2, out);
}